// Round 1
// baseline (1708.920 us; speedup 1.0000x reference)
//
#include <hip/hip_runtime.h>
#include <math.h>

#define N_NODES 100000
#define N_EDGES 3200000
#define IN_F 256
#define H 128
#define N_HOPS 4
#define SCAN_B 256
#define GEMM_BM 32

// ---------------- CSR build ----------------

__global__ void deg_kernel(const int* __restrict__ dst, int* __restrict__ deg) {
    int e = blockIdx.x * blockDim.x + threadIdx.x;
    if (e < N_EDGES) atomicAdd(&deg[dst[e]], 1);
}

__global__ void dinv_kernel(const int* __restrict__ deg, float* __restrict__ dinv) {
    int n = blockIdx.x * blockDim.x + threadIdx.x;
    if (n < N_NODES) dinv[n] = rsqrtf((float)deg[n] + 1.0f);  // +1 self-loop
}

__global__ void scan_p1(const int* __restrict__ deg, int* __restrict__ bsum) {
    __shared__ int s[SCAN_B];
    int n = blockIdx.x * SCAN_B + threadIdx.x;
    s[threadIdx.x] = (n < N_NODES) ? deg[n] : 0;
    __syncthreads();
    for (int off = SCAN_B / 2; off; off >>= 1) {
        if (threadIdx.x < off) s[threadIdx.x] += s[threadIdx.x + off];
        __syncthreads();
    }
    if (threadIdx.x == 0) bsum[blockIdx.x] = s[0];
}

__global__ void scan_p2(int* __restrict__ bsum, int nb) {
    if (blockIdx.x == 0 && threadIdx.x == 0) {
        int run = 0;
        for (int b = 0; b < nb; ++b) { int t = bsum[b]; bsum[b] = run; run += t; }
    }
}

__global__ void scan_p3(const int* __restrict__ deg, const int* __restrict__ boff,
                        int* __restrict__ rowptr) {
    __shared__ int s[SCAN_B];
    int n = blockIdx.x * SCAN_B + threadIdx.x;
    int v = (n < N_NODES) ? deg[n] : 0;
    s[threadIdx.x] = v;
    __syncthreads();
    // Hillis-Steele inclusive scan
    for (int off = 1; off < SCAN_B; off <<= 1) {
        int t = (threadIdx.x >= off) ? s[threadIdx.x - off] : 0;
        __syncthreads();
        s[threadIdx.x] += t;
        __syncthreads();
    }
    int incl = s[threadIdx.x];
    int excl = incl - v;
    if (n < N_NODES) rowptr[n] = boff[blockIdx.x] + excl;
    if (n == N_NODES - 1) rowptr[N_NODES] = boff[blockIdx.x] + incl;  // == E
}

__global__ void scatter_kernel(const int* __restrict__ src, const int* __restrict__ dst,
                               const float* __restrict__ dinv, const int* __restrict__ rowptr,
                               int* __restrict__ cursor,
                               int* __restrict__ src_sorted, float* __restrict__ w_sorted) {
    int e = blockIdx.x * blockDim.x + threadIdx.x;
    if (e >= N_EDGES) return;
    int s = src[e], d = dst[e];
    int pos = rowptr[d] + atomicAdd(&cursor[d], 1);
    src_sorted[pos] = s;
    w_sorted[pos] = dinv[s] * dinv[d];
}

// ---------------- input block: h0 = relu(X @ W0 + b0) ----------------
// block = 256 threads, BM=32 nodes/block. A-tile staged in LDS (contiguous copy).
__global__ __launch_bounds__(256) void input_gemm(const float* __restrict__ X,
                                                  const float* __restrict__ W0,
                                                  const float* __restrict__ b0,
                                                  float* __restrict__ hout) {
    __shared__ float As[GEMM_BM * IN_F];  // 32 KB
    int node0 = blockIdx.x * GEMM_BM;
    const float4* xp = (const float4*)(X + (size_t)node0 * IN_F);
    for (int i = threadIdx.x; i < GEMM_BM * IN_F / 4; i += 256)
        ((float4*)As)[i] = xp[i];
    __syncthreads();

    int f = threadIdx.x & (H - 1);
    int rg = threadIdx.x >> 7;  // 0/1: rows rg*16 .. rg*16+15
    float acc[16];
#pragma unroll
    for (int j = 0; j < 16; ++j) acc[j] = 0.f;
    for (int k = 0; k < IN_F; ++k) {
        float wv = W0[k * H + f];
#pragma unroll
        for (int j = 0; j < 16; ++j) acc[j] += As[(rg * 16 + j) * IN_F + k] * wv;
    }
    float bb = b0[f];
#pragma unroll
    for (int j = 0; j < 16; ++j) {
        int n = node0 + rg * 16 + j;
        float v = acc[j] + bb;
        hout[(size_t)n * H + f] = v > 0.f ? v : 0.f;
    }
}

// ---------------- fused hop: aggregate + bias + relu + attention gate ----------------
// one wave per node; lane l owns features 2l, 2l+1 (float2)
__global__ __launch_bounds__(256) void hop_kernel(const float* __restrict__ h_in,
                                                  float* __restrict__ h_out,
                                                  const int* __restrict__ rowptr,
                                                  const int* __restrict__ srcs,
                                                  const float* __restrict__ ws,
                                                  const float* __restrict__ dinv,
                                                  const float* __restrict__ bias,
                                                  const float* __restrict__ Wa,
                                                  const float* __restrict__ batt) {
    int wid = threadIdx.x >> 6;
    int lane = threadIdx.x & 63;
    int n = blockIdx.x * 4 + wid;
    if (n >= N_NODES) return;

    float2 hn = ((const float2*)(h_in + (size_t)n * H))[lane];
    float dd = dinv[n];
    dd = dd * dd;
    float accx = hn.x * dd, accy = hn.y * dd;  // self-loop term

    int e0 = rowptr[n], e1 = rowptr[n + 1];
    for (int base = e0; base < e1; base += 64) {
        int cnt = e1 - base;
        if (cnt > 64) cnt = 64;
        int sv = 0;
        float wv = 0.f;
        if (lane < cnt) { sv = srcs[base + lane]; wv = ws[base + lane]; }
        for (int j = 0; j < cnt; ++j) {
            int sj = __shfl(sv, j);
            float wj = __shfl(wv, j);
            float2 hv = ((const float2*)(h_in + (size_t)sj * H))[lane];
            accx += wj * hv.x;
            accy += wj * hv.y;
        }
    }

    float hkx = accx + bias[2 * lane];     hkx = hkx > 0.f ? hkx : 0.f;
    float hky = accy + bias[2 * lane + 1]; hky = hky > 0.f ? hky : 0.f;

    // attention: a = tanh( [h_k, h] . Wa + batt )
    float p = hkx * Wa[2 * lane] + hky * Wa[2 * lane + 1]
            + hn.x * Wa[H + 2 * lane] + hn.y * Wa[H + 2 * lane + 1];
#pragma unroll
    for (int off = 32; off; off >>= 1) p += __shfl_xor(p, off);
    float a = tanhf(p + batt[0]);

    float ox = a * hkx + (1.f - a) * hn.x;
    float oy = a * hky + (1.f - a) * hn.y;
    ((float2*)(h_out + (size_t)n * H))[lane] = make_float2(ox, oy);
}

// ---------------- launch ----------------

extern "C" void kernel_launch(void* const* d_in, const int* in_sizes, int n_in,
                              void* d_out, int out_size, void* d_ws, size_t ws_size,
                              hipStream_t stream) {
    const int* edge_index = (const int*)d_in[0];
    const int* src = edge_index;
    const int* dst = edge_index + N_EDGES;
    const float* features = (const float*)d_in[1];
    const float* W0 = (const float*)d_in[2];
    const float* b0 = (const float*)d_in[3];
    const float* biases = (const float*)d_in[4];
    const float* Watt = (const float*)d_in[5];
    const float* batt = (const float*)d_in[6];
    float* out = (float*)d_out;

    // workspace carve-up (all 4-byte types)
    char* p = (char*)d_ws;
    int* deg = (int*)p;          p += (size_t)N_NODES * 4;
    float* dinv = (float*)p;     p += (size_t)N_NODES * 4;
    int* rowptr = (int*)p;       p += (size_t)(N_NODES + 1) * 4;
    int* cursor = (int*)p;       p += (size_t)N_NODES * 4;
    int* bsum = (int*)p;         p += 4096;
    int* src_sorted = (int*)p;   p += (size_t)N_EDGES * 4;
    float* w_sorted = (float*)p; p += (size_t)N_EDGES * 4;
    float* hA = (float*)p;       p += (size_t)N_NODES * H * 4;  // 51.2 MB

    hipMemsetAsync(deg, 0, (size_t)N_NODES * 4, stream);
    hipMemsetAsync(cursor, 0, (size_t)N_NODES * 4, stream);

    int eb = (N_EDGES + 255) / 256;
    int nbN = (N_NODES + 255) / 256;
    deg_kernel<<<eb, 256, 0, stream>>>(dst, deg);
    dinv_kernel<<<nbN, 256, 0, stream>>>(deg, dinv);
    scan_p1<<<nbN, SCAN_B, 0, stream>>>(deg, bsum);
    scan_p2<<<1, 1, 0, stream>>>(bsum, nbN);
    scan_p3<<<nbN, SCAN_B, 0, stream>>>(deg, bsum, rowptr);
    scatter_kernel<<<eb, 256, 0, stream>>>(src, dst, dinv, rowptr, cursor, src_sorted, w_sorted);

    // h0 -> d_out; ping-pong so h4 ends in d_out
    input_gemm<<<N_NODES / GEMM_BM, 256, 0, stream>>>(features, W0, b0, out);

    float* hin = out;
    float* hout = hA;
    for (int i = 0; i < N_HOPS; ++i) {
        hop_kernel<<<(N_NODES + 3) / 4, 256, 0, stream>>>(
            hin, hout, rowptr, src_sorted, w_sorted, dinv,
            biases + (size_t)i * H, Watt + (size_t)i * 2 * H, batt + i);
        float* t = hin; hin = hout; hout = t;
    }
    // hops: out->hA->out->hA->out : final already in d_out
}

// Round 2
// 999.010 us; speedup vs baseline: 1.7106x; 1.7106x over previous
//
#include <hip/hip_runtime.h>
#include <hip/hip_fp16.h>
#include <math.h>

#define N_NODES 100000
#define N_EDGES 3200000
#define IN_F 256
#define H 128
#define N_HOPS 4
#define SCAN_B 256
#define GB_M 128
#define GB_K 32

// ---------------- CSR build ----------------

__global__ void deg_kernel(const int* __restrict__ dst, int* __restrict__ deg) {
    int e = blockIdx.x * blockDim.x + threadIdx.x;
    if (e < N_EDGES) atomicAdd(&deg[dst[e]], 1);
}

__global__ void dinv_kernel(const int* __restrict__ deg, float* __restrict__ dinv) {
    int n = blockIdx.x * blockDim.x + threadIdx.x;
    if (n < N_NODES) dinv[n] = rsqrtf((float)deg[n] + 1.0f);  // +1 self-loop
}

__global__ void scan_p1(const int* __restrict__ deg, int* __restrict__ bsum) {
    __shared__ int s[SCAN_B];
    int n = blockIdx.x * SCAN_B + threadIdx.x;
    s[threadIdx.x] = (n < N_NODES) ? deg[n] : 0;
    __syncthreads();
    for (int off = SCAN_B / 2; off; off >>= 1) {
        if (threadIdx.x < off) s[threadIdx.x] += s[threadIdx.x + off];
        __syncthreads();
    }
    if (threadIdx.x == 0) bsum[blockIdx.x] = s[0];
}

// one-block exclusive scan over nb (<=512) block sums
__global__ void scan_p2(int* __restrict__ bsum, int nb) {
    __shared__ int s[512];
    int t = threadIdx.x;
    int v0 = (t < nb) ? bsum[t] : 0;
    s[t] = v0;
    __syncthreads();
    for (int off = 1; off < 512; off <<= 1) {
        int v = (t >= off) ? s[t - off] : 0;
        __syncthreads();
        s[t] += v;
        __syncthreads();
    }
    if (t < nb) bsum[t] = s[t] - v0;  // exclusive
}

__global__ void scan_p3(const int* __restrict__ deg, const int* __restrict__ boff,
                        int* __restrict__ rowptr) {
    __shared__ int s[SCAN_B];
    int n = blockIdx.x * SCAN_B + threadIdx.x;
    int v = (n < N_NODES) ? deg[n] : 0;
    s[threadIdx.x] = v;
    __syncthreads();
    for (int off = 1; off < SCAN_B; off <<= 1) {
        int t = (threadIdx.x >= off) ? s[threadIdx.x - off] : 0;
        __syncthreads();
        s[threadIdx.x] += t;
        __syncthreads();
    }
    int incl = s[threadIdx.x];
    int excl = incl - v;
    if (n < N_NODES) rowptr[n] = boff[blockIdx.x] + excl;
    if (n == N_NODES - 1) rowptr[N_NODES] = boff[blockIdx.x] + incl;
}

__global__ void scatter_kernel(const int* __restrict__ src, const int* __restrict__ dst,
                               const float* __restrict__ dinv, const int* __restrict__ rowptr,
                               int* __restrict__ cursor, uint2* __restrict__ edges) {
    int e = blockIdx.x * blockDim.x + threadIdx.x;
    if (e >= N_EDGES) return;
    int s = src[e], d = dst[e];
    int pos = rowptr[d] + atomicAdd(&cursor[d], 1);
    edges[pos] = make_uint2((unsigned)s, __float_as_uint(dinv[s] * dinv[d]));
}

// ---------------- input block: h0 = fp16(relu(X @ W0 + b0)) ----------------
// 128x128 tile, BK=32, 256 threads, 8x8 register tile; A staged TRANSPOSED in LDS.
__global__ __launch_bounds__(256) void input_gemm(const float* __restrict__ X,
                                                  const float* __restrict__ W0,
                                                  const float* __restrict__ b0,
                                                  __half* __restrict__ h16) {
    __shared__ float AsT[GB_K][GB_M + 4];   // [k][row], padded
    __shared__ float Ws[GB_K][H];
    int node0 = blockIdx.x * GB_M;
    int tid = threadIdx.x;
    int tx = tid & 15;   // col group: cols tx*8 .. tx*8+7
    int ty = tid >> 4;   // row group: rows ty*8 .. ty*8+7

    float acc[8][8];
#pragma unroll
    for (int i = 0; i < 8; ++i)
#pragma unroll
        for (int j = 0; j < 8; ++j) acc[i][j] = 0.f;

    for (int k0 = 0; k0 < IN_F; k0 += GB_K) {
        // stage A (transposed): 128 rows x 32 k
#pragma unroll
        for (int j = 0; j < 4; ++j) {
            int idx = tid + 256 * j;
            int row = idx >> 3, c4 = idx & 7;
            float4 v = make_float4(0.f, 0.f, 0.f, 0.f);
            if (node0 + row < N_NODES)
                v = *(const float4*)(X + (size_t)(node0 + row) * IN_F + k0 + c4 * 4);
            AsT[c4 * 4 + 0][row] = v.x;
            AsT[c4 * 4 + 1][row] = v.y;
            AsT[c4 * 4 + 2][row] = v.z;
            AsT[c4 * 4 + 3][row] = v.w;
        }
        // stage W: 32 rows x 128 cols
#pragma unroll
        for (int j = 0; j < 4; ++j) {
            int idx = tid + 256 * j;
            int row = idx >> 5, c4 = idx & 31;
            *(float4*)&Ws[row][c4 * 4] = *(const float4*)(W0 + (size_t)(k0 + row) * H + c4 * 4);
        }
        __syncthreads();
#pragma unroll
        for (int kk = 0; kk < GB_K; ++kk) {
            float a[8], w[8];
            *(float4*)&a[0] = *(const float4*)&AsT[kk][ty * 8];
            *(float4*)&a[4] = *(const float4*)&AsT[kk][ty * 8 + 4];
            *(float4*)&w[0] = *(const float4*)&Ws[kk][tx * 8];
            *(float4*)&w[4] = *(const float4*)&Ws[kk][tx * 8 + 4];
#pragma unroll
            for (int i = 0; i < 8; ++i)
#pragma unroll
                for (int j = 0; j < 8; ++j) acc[i][j] += a[i] * w[j];
        }
        __syncthreads();
    }

#pragma unroll
    for (int i = 0; i < 8; ++i) {
        int n = node0 + ty * 8 + i;
        if (n < N_NODES) {
            union { float4 f4; __half2 h2[4]; } u;
#pragma unroll
            for (int jj = 0; jj < 4; ++jj) {
                float v0 = acc[i][2 * jj + 0] + b0[tx * 8 + 2 * jj + 0];
                float v1 = acc[i][2 * jj + 1] + b0[tx * 8 + 2 * jj + 1];
                v0 = v0 > 0.f ? v0 : 0.f;
                v1 = v1 > 0.f ? v1 : 0.f;
                u.h2[jj] = __floats2half2_rn(v0, v1);
            }
            *(float4*)(h16 + (size_t)n * H + tx * 8) = u.f4;
        }
    }
}

// ---------------- fused hop ----------------
// one wave per node; lane l owns features 2l, 2l+1 (half2 gather = 4B/lane)
__global__ __launch_bounds__(256) void hop_kernel(const __half* __restrict__ h_in,
                                                  __half* __restrict__ h16_out,
                                                  float* __restrict__ out32,
                                                  const int* __restrict__ rowptr,
                                                  const uint2* __restrict__ edges,
                                                  const float* __restrict__ dinv,
                                                  const float* __restrict__ bias,
                                                  const float* __restrict__ Wa,
                                                  const float* __restrict__ batt) {
    int wid = threadIdx.x >> 6;
    int lane = threadIdx.x & 63;
    int n = blockIdx.x * 4 + wid;
    if (n >= N_NODES) return;

    float2 hn = __half22float2(((const __half2*)(h_in + (size_t)n * H))[lane]);
    float dd = dinv[n];
    dd = dd * dd;
    float accx = hn.x * dd, accy = hn.y * dd;  // self-loop term

    int e0 = rowptr[n], e1 = rowptr[n + 1];
    for (int base = e0; base < e1; base += 64) {
        int cnt = e1 - base;
        if (cnt > 64) cnt = 64;
        int sv = 0;
        float wv = 0.f;
        if (lane < cnt) {
            uint2 ev = edges[base + lane];
            sv = (int)ev.x;
            wv = __uint_as_float(ev.y);
        }
        int j = 0;
        for (; j + 3 < cnt; j += 4) {
            int s0 = __shfl(sv, j + 0), s1 = __shfl(sv, j + 1);
            int s2 = __shfl(sv, j + 2), s3 = __shfl(sv, j + 3);
            float w0 = __shfl(wv, j + 0), w1 = __shfl(wv, j + 1);
            float w2 = __shfl(wv, j + 2), w3 = __shfl(wv, j + 3);
            float2 g0 = __half22float2(((const __half2*)(h_in + (size_t)s0 * H))[lane]);
            float2 g1 = __half22float2(((const __half2*)(h_in + (size_t)s1 * H))[lane]);
            float2 g2 = __half22float2(((const __half2*)(h_in + (size_t)s2 * H))[lane]);
            float2 g3 = __half22float2(((const __half2*)(h_in + (size_t)s3 * H))[lane]);
            accx += w0 * g0.x + w1 * g1.x + w2 * g2.x + w3 * g3.x;
            accy += w0 * g0.y + w1 * g1.y + w2 * g2.y + w3 * g3.y;
        }
        for (; j < cnt; ++j) {
            int sj = __shfl(sv, j);
            float wj = __shfl(wv, j);
            float2 g = __half22float2(((const __half2*)(h_in + (size_t)sj * H))[lane]);
            accx += wj * g.x;
            accy += wj * g.y;
        }
    }

    float hkx = accx + bias[2 * lane];     hkx = hkx > 0.f ? hkx : 0.f;
    float hky = accy + bias[2 * lane + 1]; hky = hky > 0.f ? hky : 0.f;

    // attention: a = tanh( [h_k, h] . Wa + batt )
    float p = hkx * Wa[2 * lane] + hky * Wa[2 * lane + 1]
            + hn.x * Wa[H + 2 * lane] + hn.y * Wa[H + 2 * lane + 1];
#pragma unroll
    for (int off = 32; off; off >>= 1) p += __shfl_xor(p, off);
    float a = tanhf(p + batt[0]);

    float ox = a * hkx + (1.f - a) * hn.x;
    float oy = a * hky + (1.f - a) * hn.y;
    if (out32) {
        ((float2*)(out32 + (size_t)n * H))[lane] = make_float2(ox, oy);
    } else {
        ((__half2*)(h16_out + (size_t)n * H))[lane] = __floats2half2_rn(ox, oy);
    }
}

// ---------------- launch ----------------

extern "C" void kernel_launch(void* const* d_in, const int* in_sizes, int n_in,
                              void* d_out, int out_size, void* d_ws, size_t ws_size,
                              hipStream_t stream) {
    const int* edge_index = (const int*)d_in[0];
    const int* src = edge_index;
    const int* dst = edge_index + N_EDGES;
    const float* features = (const float*)d_in[1];
    const float* W0 = (const float*)d_in[2];
    const float* b0 = (const float*)d_in[3];
    const float* biases = (const float*)d_in[4];
    const float* Watt = (const float*)d_in[5];
    const float* batt = (const float*)d_in[6];
    float* out = (float*)d_out;

    // workspace carve-up, 256B-aligned chunks
    size_t off = 0;
    char* base = (char*)d_ws;
    auto carve = [&](size_t bytes) -> void* {
        void* q = base + off;
        off += (bytes + 255) & ~(size_t)255;
        return q;
    };
    int* deg = (int*)carve((size_t)N_NODES * 4);
    float* dinv = (float*)carve((size_t)N_NODES * 4);
    int* rowptr = (int*)carve((size_t)(N_NODES + 1) * 4);
    int* cursor = (int*)carve((size_t)N_NODES * 4);
    int* bsum = (int*)carve(4096);
    uint2* edges = (uint2*)carve((size_t)N_EDGES * 8);
    __half* h16A = (__half*)carve((size_t)N_NODES * H * 2);
    __half* h16B = (__half*)carve((size_t)N_NODES * H * 2);

    hipMemsetAsync(deg, 0, (size_t)N_NODES * 4, stream);
    hipMemsetAsync(cursor, 0, (size_t)N_NODES * 4, stream);

    int eb = (N_EDGES + 255) / 256;
    int nbN = (N_NODES + 255) / 256;  // 391
    deg_kernel<<<eb, 256, 0, stream>>>(dst, deg);
    dinv_kernel<<<nbN, 256, 0, stream>>>(deg, dinv);
    scan_p1<<<nbN, SCAN_B, 0, stream>>>(deg, bsum);
    scan_p2<<<1, 512, 0, stream>>>(bsum, nbN);
    scan_p3<<<nbN, SCAN_B, 0, stream>>>(deg, bsum, rowptr);
    scatter_kernel<<<eb, 256, 0, stream>>>(src, dst, dinv, rowptr, cursor, edges);

    input_gemm<<<(N_NODES + GB_M - 1) / GB_M, 256, 0, stream>>>(features, W0, b0, h16A);

    __half* hin = h16A;
    __half* hout = h16B;
    for (int i = 0; i < N_HOPS; ++i) {
        bool last = (i == N_HOPS - 1);
        hop_kernel<<<(N_NODES + 3) / 4, 256, 0, stream>>>(
            hin, hout, last ? out : nullptr, rowptr, edges, dinv,
            biases + (size_t)i * H, Watt + (size_t)i * 2 * H, batt + i);
        __half* t = hin; hin = hout; hout = t;
    }
}